// Round 2
// baseline (508.034 us; speedup 1.0000x reference)
//
#include <hip/hip_runtime.h>

#define B_   64
#define P_   12273
#define J_   80
#define MOT_ 94
#define K_   64
#define H_   128
#define Q_   340      // NB*WN
#define NE_  36819    // P*3
#define MK_  6016     // MOT*K

// ---- K0: init detailkey accumulator with bias bd; zero loss accumulators
__global__ void k_init(const float* __restrict__ bd, float* __restrict__ dk,
                       float* __restrict__ lacc){
  int i = blockIdx.x * 256 + threadIdx.x;
  if (i < B_ * Q_) dk[i] = bd[i % Q_];
  if (i < 2) lacc[i] = 0.f;
}

// ---- K1: per-(b,j) FieldNet: field_input -> 2-layer MLP -> pose/trans -> G[b,j] = [R|T] (3x4)
__global__ __launch_bounds__(128) void k_fieldnet(
    const float* __restrict__ query, const float* __restrict__ mwl,
    const float* __restrict__ tm,    const float* __restrict__ W1,
    const float* __restrict__ b1,    const float* __restrict__ W2,
    const float* __restrict__ b2,    const float* __restrict__ cps,
    const float* __restrict__ cpm,   const float* __restrict__ cts,
    const float* __restrict__ ctm,   float* __restrict__ G)
{
  int bj = blockIdx.x;
  int b = bj / J_, l = bj % J_;
  __shared__ float h_s[3 + K_];
  __shared__ float hid_s[H_];
  __shared__ float rt_s[6];
  int t = threadIdx.x;
  if (t < K_) {
    float acc = 0.f;
    const float* tp = tm + (size_t)b * MK_ + t;
    const float* mp = mwl + l * MOT_;
    for (int j = 0; j < MOT_; j++){
      float w = mp[j]; w = w > 0.f ? w : 0.f;
      acc = fmaf(w, tp[j * K_], acc);
    }
    h_s[3 + t] = acc;
  } else if (t < K_ + 3) {
    h_s[t - K_] = query[(size_t)bj * 3 + (t - K_)];
  }
  __syncthreads();
  {
    float acc = b1[t];
    for (int i = 0; i < 3 + K_; i++) acc = fmaf(h_s[i], W1[i * H_ + t], acc);
    hid_s[t] = acc > 0.f ? acc : 0.f;
  }
  __syncthreads();
  if (t < 6){
    float acc = b2[t];
    for (int i = 0; i < H_; i++) acc = fmaf(hid_s[i], W2[i * 6 + t], acc);
    rt_s[t] = acc;
  }
  __syncthreads();
  if (t == 0){
    const float D2R = 0.017453292519943295f;
    float ax = fmaf(rt_s[0], cps[0], cpm[0]) * D2R;
    float ay = fmaf(rt_s[1], cps[1], cpm[1]) * D2R;
    float az = fmaf(rt_s[2], cps[2], cpm[2]) * D2R;
    float tx = fmaf(h_s[0] + rt_s[3], cts[0], ctm[0]);
    float ty = fmaf(h_s[1] + rt_s[4], cts[1], ctm[1]);
    float tz = fmaf(h_s[2] + rt_s[5], cts[2], ctm[2]);
    float sx, cx, sy, cy, sz, cz;
    sincosf(ax, &sx, &cx); sincosf(ay, &sy, &cy); sincosf(az, &sz, &cz);
    float* g = G + (size_t)bj * 12;
    g[0] = cz * cy; g[1] = cz * sy * sx - sz * cx; g[2]  = cz * sy * cx + sz * sx; g[3]  = tx;
    g[4] = sz * cy; g[5] = sz * sy * sx + cz * cx; g[6]  = sz * sy * cx - cz * sx; g[7]  = ty;
    g[8] = -sy;     g[9] = cy * sx;                g[10] = cy * cx;                g[11] = tz;
  }
}

// ---- K2: detailkey GEMM [64,6016]x[6016,340]; Wd read exactly once.
//          grid (6 q-tiles, 16 K-splits); wave w handles b in [16w,16w+16)
__global__ __launch_bounds__(256) void k_dkey(
    const float* __restrict__ tm, const float* __restrict__ Wd, float* __restrict__ dk)
{
  int lane = threadIdx.x & 63;
  int wv = __builtin_amdgcn_readfirstlane(threadIdx.x >> 6);
  int b0 = wv * 16;
  int q = blockIdx.x * 64 + lane;
  bool vq = q < Q_;
  int m0 = blockIdx.y * (MK_ / 16);
  float acc[16];
  #pragma unroll
  for (int i = 0; i < 16; i++) acc[i] = 0.f;
  const float* tb = tm + (size_t)b0 * MK_;     // wave-uniform base -> scalar loads
  for (int m = m0; m < m0 + MK_ / 16; m++){
    float wd = vq ? Wd[(size_t)m * Q_ + q] : 0.f;
    #pragma unroll
    for (int i = 0; i < 16; i++)
      acc[i] = fmaf(tb[(size_t)i * MK_ + m], wd, acc[i]);
  }
  if (vq){
    #pragma unroll
    for (int i = 0; i < 16; i++)
      atomicAdd(&dk[(b0 + i) * Q_ + q], acc[i]);
  }
}

// ---- K3a: detail einsum [64,340]x[340,36819]; DPSD read once; fused sum(DPSD^2);
//           writes det_res (std/mean applied) into out[1..] (staging)
__global__ __launch_bounds__(256) void k_detail(
    const float* __restrict__ DPSD, const float* __restrict__ dk,
    const float* __restrict__ rstd, const float* __restrict__ rmean,
    float* __restrict__ out, float* __restrict__ lacc)
{
  int lane = threadIdx.x & 63;
  int wv = __builtin_amdgcn_readfirstlane(threadIdx.x >> 6);  // wave id 0..3 -> b-range
  int b0 = wv * 16;
  int e0 = blockIdx.x * 128;
  int ea = e0 + lane;          // max 287*128+63 = 36799 < NE_
  int eb = ea + 64;
  bool vb = eb < NE_;
  const float* dkb = dk + b0 * Q_;   // wave-uniform base -> scalar loads
  float acc[16][2];
  #pragma unroll
  for (int i = 0; i < 16; i++){ acc[i][0] = 0.f; acc[i][1] = 0.f; }
  float sq = 0.f;
  for (int q = 0; q < Q_; q++){
    size_t ro = (size_t)q * NE_;
    float d0 = DPSD[ro + ea];
    float d1 = vb ? DPSD[ro + eb] : 0.f;
    if (wv == 0) sq = fmaf(d0, d0, fmaf(d1, d1, sq));
    #pragma unroll
    for (int i = 0; i < 16; i++){
      float w = dkb[i * Q_ + q];
      acc[i][0] = fmaf(w, d0, acc[i][0]);
      acc[i][1] = fmaf(w, d1, acc[i][1]);
    }
  }
  float s3[3], m3[3];
  #pragma unroll
  for (int x = 0; x < 3; x++){ s3[x] = rstd[x]; m3[x] = rmean[x]; }
  int xa = ea % 3, xb = eb % 3;
  #pragma unroll
  for (int i = 0; i < 16; i++){
    size_t ob = 1 + (size_t)(b0 + i) * NE_;
    out[ob + ea] = fmaf(acc[i][0], s3[xa], m3[xa]);
    if (vb) out[ob + eb] = fmaf(acc[i][1], s3[xb], m3[xb]);
  }
  if (wv == 0){
    #pragma unroll
    for (int off = 32; off; off >>= 1) sq += __shfl_xor(sq, off);
    if (lane == 0) atomicAdd(&lacc[1], sq);
  }
}

// ---- K3b: LBS skinning (sum over 80 joints), add staged det_res, final out, L1 loss partials
__global__ __launch_bounds__(256) void k_skin(
    const float* __restrict__ G, const float* __restrict__ skin,
    const float* __restrict__ rest, const float* __restrict__ in_pc,
    float* __restrict__ out, float* __restrict__ lacc)
{
  __shared__ float w_s[16 * 256];    // [j_local][p_local], stride-1 lane reads
  int t = threadIdx.x;
  int p = blockIdx.x * 256 + t;
  int b0 = blockIdx.y * 4;
  bool vp = p < P_;
  float vx = 0.f, vy = 0.f, vz = 0.f;
  if (vp){ vx = rest[p * 3]; vy = rest[p * 3 + 1]; vz = rest[p * 3 + 2]; }
  float acc[4][3];
  #pragma unroll
  for (int bb = 0; bb < 4; bb++){ acc[bb][0] = acc[bb][1] = acc[bb][2] = 0.f; }
  const float* wp = skin + (size_t)p * J_;
  for (int jc = 0; jc < 5; jc++){
    __syncthreads();
    if (vp){
      #pragma unroll
      for (int r = 0; r < 4; r++){
        float4 u = *(const float4*)(wp + jc * 16 + r * 4);   // 16B aligned: 4*(80p+16jc+4r)
        w_s[(r * 4 + 0) * 256 + t] = u.x;
        w_s[(r * 4 + 1) * 256 + t] = u.y;
        w_s[(r * 4 + 2) * 256 + t] = u.z;
        w_s[(r * 4 + 3) * 256 + t] = u.w;
      }
    } else {
      #pragma unroll
      for (int jl = 0; jl < 16; jl++) w_s[jl * 256 + t] = 0.f;
    }
    __syncthreads();
    for (int j = 0; j < 16; j++){
      int jjj = jc * 16 + j;
      float wj = w_s[j * 256 + t];
      #pragma unroll
      for (int bb = 0; bb < 4; bb++){
        const float* g = G + ((size_t)(b0 + bb) * J_ + jjj) * 12;  // uniform -> s_load x12 contiguous
        acc[bb][0] = fmaf(wj, fmaf(g[0], vx, fmaf(g[1], vy, fmaf(g[2],  vz, g[3]))),  acc[bb][0]);
        acc[bb][1] = fmaf(wj, fmaf(g[4], vx, fmaf(g[5], vy, fmaf(g[6],  vz, g[7]))),  acc[bb][1]);
        acc[bb][2] = fmaf(wj, fmaf(g[8], vx, fmaf(g[9], vy, fmaf(g[10], vz, g[11]))), acc[bb][2]);
      }
    }
  }
  float lsum = 0.f;
  if (vp){
    #pragma unroll
    for (int bb = 0; bb < 4; bb++){
      size_t base = ((size_t)(b0 + bb) * P_ + p) * 3;
      #pragma unroll
      for (int x = 0; x < 3; x++){
        float v = acc[bb][x] + out[1 + base + x];
        lsum += fabsf(in_pc[base + x] - v);
        out[1 + base + x] = v;
      }
    }
  }
  #pragma unroll
  for (int off = 32; off; off >>= 1) lsum += __shfl_xor(lsum, off);
  if ((t & 63) == 0) atomicAdd(&lacc[0], lsum);
}

// ---- K4: finalize scalar loss
__global__ void k_finalize(const float* __restrict__ lacc, float* __restrict__ out){
  if (threadIdx.x == 0 && blockIdx.x == 0){
    float loss = lacc[0] * (1.f / 2356416.f) + 1e-4f * (lacc[1] * (1.f / 12518460.f));
    out[0] = loss;
  }
}

extern "C" void kernel_launch(void* const* d_in, const int* in_sizes, int n_in,
                              void* d_out, int out_size, void* d_ws, size_t ws_size,
                              hipStream_t stream){
  const float* in_pc = (const float*)d_in[0];
  const float* rest  = (const float*)d_in[2];
  const float* skin  = (const float*)d_in[3];
  const float* mwl   = (const float*)d_in[4];
  const float* query = (const float*)d_in[5];
  const float* cps   = (const float*)d_in[6];
  const float* cpm   = (const float*)d_in[7];
  const float* cts   = (const float*)d_in[8];
  const float* ctm   = (const float*)d_in[9];
  const float* W1    = (const float*)d_in[10];
  const float* b1    = (const float*)d_in[11];
  const float* W2    = (const float*)d_in[12];
  const float* b2    = (const float*)d_in[13];
  const float* tm    = (const float*)d_in[14];
  const float* Wd    = (const float*)d_in[15];
  const float* bd    = (const float*)d_in[16];
  const float* DPSD  = (const float*)d_in[17];
  const float* rstd  = (const float*)d_in[18];
  const float* rmean = (const float*)d_in[19];
  float* out = (float*)d_out;

  float* ws   = (float*)d_ws;
  float* G    = ws;                    // 64*80*12 = 61440 f32
  float* dk   = ws + 61440;            // 64*340  = 21760 f32
  float* lacc = ws + 61440 + 21760;    // 2 f32  (total ~333 KB)

  k_init    <<<86, 256, 0, stream>>>(bd, dk, lacc);
  k_fieldnet<<<B_ * J_, 128, 0, stream>>>(query, mwl, tm, W1, b1, W2, b2,
                                          cps, cpm, cts, ctm, G);
  k_dkey    <<<dim3(6, 16), 256, 0, stream>>>(tm, Wd, dk);
  k_detail  <<<288, 256, 0, stream>>>(DPSD, dk, rstd, rmean, out, lacc);
  k_skin    <<<dim3(48, 16), 256, 0, stream>>>(G, skin, rest, in_pc, out, lacc);
  k_finalize<<<1, 64, 0, stream>>>(lacc, out);
}

// Round 3
// 416.264 us; speedup vs baseline: 1.2205x; 1.2205x over previous
//
#include <hip/hip_runtime.h>

#define B_   64
#define P_   12273
#define J_   80
#define MOT_ 94
#define K_   64
#define H_   128
#define Q_   340      // NB*WN
#define NE_  36819    // P*3
#define MK_  6016     // MOT*K

// ---- K0: init transposed detailkey accumulator dk_t[q*64+b] = bd[q]; zero loss accs
__global__ void k_init(const float* __restrict__ bd, float* __restrict__ dk_t,
                       float* __restrict__ lacc){
  int i = blockIdx.x * 256 + threadIdx.x;
  if (i < B_ * Q_) dk_t[i] = bd[i >> 6];
  if (i < 2) lacc[i] = 0.f;
}

// ---- K1: per-(b,j) FieldNet (unchanged from round 2 — correct; revisit if hot)
__global__ __launch_bounds__(128) void k_fieldnet(
    const float* __restrict__ query, const float* __restrict__ mwl,
    const float* __restrict__ tm,    const float* __restrict__ W1,
    const float* __restrict__ b1,    const float* __restrict__ W2,
    const float* __restrict__ b2,    const float* __restrict__ cps,
    const float* __restrict__ cpm,   const float* __restrict__ cts,
    const float* __restrict__ ctm,   float* __restrict__ G)
{
  int bj = blockIdx.x;
  int b = bj / J_, l = bj % J_;
  __shared__ float h_s[3 + K_];
  __shared__ float hid_s[H_];
  __shared__ float rt_s[6];
  int t = threadIdx.x;
  if (t < K_) {
    float acc = 0.f;
    const float* tp = tm + (size_t)b * MK_ + t;
    const float* mp = mwl + l * MOT_;
    for (int j = 0; j < MOT_; j++){
      float w = mp[j]; w = w > 0.f ? w : 0.f;
      acc = fmaf(w, tp[j * K_], acc);
    }
    h_s[3 + t] = acc;
  } else if (t < K_ + 3) {
    h_s[t - K_] = query[(size_t)bj * 3 + (t - K_)];
  }
  __syncthreads();
  {
    float acc = b1[t];
    for (int i = 0; i < 3 + K_; i++) acc = fmaf(h_s[i], W1[i * H_ + t], acc);
    hid_s[t] = acc > 0.f ? acc : 0.f;
  }
  __syncthreads();
  if (t < 6){
    float acc = b2[t];
    for (int i = 0; i < H_; i++) acc = fmaf(hid_s[i], W2[i * 6 + t], acc);
    rt_s[t] = acc;
  }
  __syncthreads();
  if (t == 0){
    const float D2R = 0.017453292519943295f;
    float ax = fmaf(rt_s[0], cps[0], cpm[0]) * D2R;
    float ay = fmaf(rt_s[1], cps[1], cpm[1]) * D2R;
    float az = fmaf(rt_s[2], cps[2], cpm[2]) * D2R;
    float tx = fmaf(h_s[0] + rt_s[3], cts[0], ctm[0]);
    float ty = fmaf(h_s[1] + rt_s[4], cts[1], ctm[1]);
    float tz = fmaf(h_s[2] + rt_s[5], cts[2], ctm[2]);
    float sx, cx, sy, cy, sz, cz;
    sincosf(ax, &sx, &cx); sincosf(ay, &sy, &cy); sincosf(az, &sz, &cz);
    float* g = G + (size_t)bj * 12;
    g[0] = cz * cy; g[1] = cz * sy * sx - sz * cx; g[2]  = cz * sy * cx + sz * sx; g[3]  = tx;
    g[4] = sz * cy; g[5] = sz * sy * sx + cz * cx; g[6]  = sz * sy * cx - cz * sx; g[7]  = ty;
    g[8] = -sy;     g[9] = cy * sx;                g[10] = cy * cx;                g[11] = tz;
  }
}

// ---- K2: detailkey GEMM [64,6016]x[6016,340] -> dk_t[q,b].
//          grid (6 q-tiles, 94 m-splits of 64). tm chunk staged in LDS,
//          read back as broadcast ds_read_b128. Wd read exactly once, coalesced.
__global__ __launch_bounds__(256) void k_dkey(
    const float* __restrict__ tm, const float* __restrict__ Wd,
    float* __restrict__ dk_t)
{
  __shared__ float tm_s[64 * 68];          // [b][m], row pad 68 (16B-aligned rows)
  int t = threadIdx.x;
  int m0 = blockIdx.y * 64;
  {
    int b = t >> 2, qu = t & 3;
    const float* src = tm + (size_t)b * MK_ + m0 + qu * 16;
    float* dst = tm_s + b * 68 + qu * 16;
    #pragma unroll
    for (int k = 0; k < 4; k++)
      *(float4*)(dst + 4 * k) = *(const float4*)(src + 4 * k);
  }
  __syncthreads();
  int lane = t & 63;
  int wv = __builtin_amdgcn_readfirstlane(t >> 6);
  int b0 = wv * 16;
  int q = blockIdx.x * 64 + lane;
  bool vq = q < Q_;
  float acc[16];
  #pragma unroll
  for (int i = 0; i < 16; i++) acc[i] = 0.f;
  for (int mm = 0; mm < 64; mm += 4){
    float wd0 = vq ? Wd[(size_t)(m0 + mm + 0) * Q_ + q] : 0.f;
    float wd1 = vq ? Wd[(size_t)(m0 + mm + 1) * Q_ + q] : 0.f;
    float wd2 = vq ? Wd[(size_t)(m0 + mm + 2) * Q_ + q] : 0.f;
    float wd3 = vq ? Wd[(size_t)(m0 + mm + 3) * Q_ + q] : 0.f;
    #pragma unroll
    for (int i = 0; i < 16; i++){
      float4 tv = *(const float4*)(tm_s + (b0 + i) * 68 + mm);   // broadcast b128
      acc[i] = fmaf(tv.x, wd0, acc[i]);
      acc[i] = fmaf(tv.y, wd1, acc[i]);
      acc[i] = fmaf(tv.z, wd2, acc[i]);
      acc[i] = fmaf(tv.w, wd3, acc[i]);
    }
  }
  if (vq){
    #pragma unroll
    for (int i = 0; i < 16; i++)
      atomicAdd(&dk_t[q * 64 + b0 + i], acc[i]);
  }
}

// ---- K3a: detail einsum [64,340]x[340,36819]; DPSD read once (all 64 b per block);
//           dk via uniform s_load_dwordx8; fused sum(DPSD^2); writes staged det_res
__global__ __launch_bounds__(512) void k_detail(
    const float* __restrict__ DPSD, const float* __restrict__ dk_t,
    const float* __restrict__ rstd, const float* __restrict__ rmean,
    float* __restrict__ out, float* __restrict__ lacc)
{
  int t = threadIdx.x;
  int lane = t & 63;
  int wv = __builtin_amdgcn_readfirstlane(t >> 6);   // 0..7
  int b0 = wv * 8;
  int e = blockIdx.x * 64 + lane;
  bool ve = e < NE_;
  const float* dkb = dk_t + b0;
  float acc[8];
  #pragma unroll
  for (int i = 0; i < 8; i++) acc[i] = 0.f;
  float sq = 0.f;
  for (int q = 0; q < Q_; q++){
    float d = ve ? DPSD[(size_t)q * NE_ + e] : 0.f;
    const float* dq = dkb + q * 64;                  // uniform -> s_load_dwordx8
    if (wv == 0) sq = fmaf(d, d, sq);
    #pragma unroll
    for (int i = 0; i < 8; i++) acc[i] = fmaf(dq[i], d, acc[i]);
  }
  if (ve){
    int x = e % 3;
    float s = rstd[x], m = rmean[x];
    #pragma unroll
    for (int i = 0; i < 8; i++)
      out[1 + (size_t)(b0 + i) * NE_ + e] = fmaf(acc[i], s, m);
  }
  if (wv == 0){
    #pragma unroll
    for (int off = 32; off; off >>= 1) sq += __shfl_xor(sq, off);
    if (lane == 0) atomicAdd(&lacc[1], sq);
  }
}

// ---- K3b: LBS skinning; G staged in LDS (broadcast b128 reads), weights in regs
__global__ __launch_bounds__(256) void k_skin(
    const float* __restrict__ G, const float* __restrict__ skin,
    const float* __restrict__ rest, const float* __restrict__ in_pc,
    float* __restrict__ out, float* __restrict__ lacc)
{
  __shared__ float G_s[4 * J_ * 12];       // 3840 f32 = 15.4 KB
  int t = threadIdx.x;
  int p = blockIdx.x * 256 + t;
  int b0 = blockIdx.y * 4;
  for (int idx = t; idx < 4 * J_ * 12; idx += 256)
    G_s[idx] = G[(size_t)b0 * J_ * 12 + idx];
  bool vp = p < P_;
  float vx = 0.f, vy = 0.f, vz = 0.f;
  if (vp){ vx = rest[p * 3]; vy = rest[p * 3 + 1]; vz = rest[p * 3 + 2]; }
  float acc[4][3];
  #pragma unroll
  for (int bb = 0; bb < 4; bb++){ acc[bb][0] = acc[bb][1] = acc[bb][2] = 0.f; }
  __syncthreads();
  const float* wp = skin + (size_t)p * J_;
  for (int jc = 0; jc < 5; jc++){
    float wr[16];
    if (vp){
      #pragma unroll
      for (int r = 0; r < 4; r++){
        float4 u = *(const float4*)(wp + jc * 16 + r * 4);
        wr[r * 4 + 0] = u.x; wr[r * 4 + 1] = u.y;
        wr[r * 4 + 2] = u.z; wr[r * 4 + 3] = u.w;
      }
    } else {
      #pragma unroll
      for (int j = 0; j < 16; j++) wr[j] = 0.f;
    }
    int jbase = jc * 16;
    #pragma unroll
    for (int j = 0; j < 16; j++){
      #pragma unroll
      for (int bb = 0; bb < 4; bb++){
        const float* gp = G_s + (bb * J_ + jbase + j) * 12;
        float4 g0 = *(const float4*)(gp + 0);
        float4 g1 = *(const float4*)(gp + 4);
        float4 g2 = *(const float4*)(gp + 8);
        acc[bb][0] = fmaf(wr[j], fmaf(g0.x, vx, fmaf(g0.y, vy, fmaf(g0.z, vz, g0.w))), acc[bb][0]);
        acc[bb][1] = fmaf(wr[j], fmaf(g1.x, vx, fmaf(g1.y, vy, fmaf(g1.z, vz, g1.w))), acc[bb][1]);
        acc[bb][2] = fmaf(wr[j], fmaf(g2.x, vx, fmaf(g2.y, vy, fmaf(g2.z, vz, g2.w))), acc[bb][2]);
      }
    }
  }
  float lsum = 0.f;
  if (vp){
    #pragma unroll
    for (int bb = 0; bb < 4; bb++){
      size_t base = ((size_t)(b0 + bb) * P_ + p) * 3;
      #pragma unroll
      for (int x = 0; x < 3; x++){
        float v = acc[bb][x] + out[1 + base + x];
        lsum += fabsf(in_pc[base + x] - v);
        out[1 + base + x] = v;
      }
    }
  }
  #pragma unroll
  for (int off = 32; off; off >>= 1) lsum += __shfl_xor(lsum, off);
  if ((t & 63) == 0) atomicAdd(&lacc[0], lsum);
}

// ---- K4: finalize scalar loss
__global__ void k_finalize(const float* __restrict__ lacc, float* __restrict__ out){
  if (threadIdx.x == 0 && blockIdx.x == 0){
    float loss = lacc[0] * (1.f / 2356416.f) + 1e-4f * (lacc[1] * (1.f / 12518460.f));
    out[0] = loss;
  }
}

extern "C" void kernel_launch(void* const* d_in, const int* in_sizes, int n_in,
                              void* d_out, int out_size, void* d_ws, size_t ws_size,
                              hipStream_t stream){
  const float* in_pc = (const float*)d_in[0];
  const float* rest  = (const float*)d_in[2];
  const float* skin  = (const float*)d_in[3];
  const float* mwl   = (const float*)d_in[4];
  const float* query = (const float*)d_in[5];
  const float* cps   = (const float*)d_in[6];
  const float* cpm   = (const float*)d_in[7];
  const float* cts   = (const float*)d_in[8];
  const float* ctm   = (const float*)d_in[9];
  const float* W1    = (const float*)d_in[10];
  const float* b1    = (const float*)d_in[11];
  const float* W2    = (const float*)d_in[12];
  const float* b2    = (const float*)d_in[13];
  const float* tm    = (const float*)d_in[14];
  const float* Wd    = (const float*)d_in[15];
  const float* bd    = (const float*)d_in[16];
  const float* DPSD  = (const float*)d_in[17];
  const float* rstd  = (const float*)d_in[18];
  const float* rmean = (const float*)d_in[19];
  float* out = (float*)d_out;

  float* ws   = (float*)d_ws;
  float* G    = ws;                    // 64*80*12 = 61440 f32
  float* dk_t = ws + 61440;            // 340*64  = 21760 f32 (transposed [q][b])
  float* lacc = ws + 61440 + 21760;    // 2 f32

  k_init    <<<86, 256, 0, stream>>>(bd, dk_t, lacc);
  k_fieldnet<<<B_ * J_, 128, 0, stream>>>(query, mwl, tm, W1, b1, W2, b2,
                                          cps, cpm, cts, ctm, G);
  k_dkey    <<<dim3(6, 94), 256, 0, stream>>>(tm, Wd, dk_t);
  k_detail  <<<576, 512, 0, stream>>>(DPSD, dk_t, rstd, rmean, out, lacc);
  k_skin    <<<dim3(48, 16), 256, 0, stream>>>(G, skin, rest, in_pc, out, lacc);
  k_finalize<<<1, 64, 0, stream>>>(lacc, out);
}

// Round 4
// 362.349 us; speedup vs baseline: 1.4021x; 1.1488x over previous
//
#include <hip/hip_runtime.h>

#define B_   64
#define P_   12273
#define J_   80
#define MOT_ 94
#define K_   64
#define H_   128
#define Q_   340      // NB*WN
#define NE_  36819    // P*3
#define MK_  6016     // MOT*K

// ---- K0: zero loss accumulators
__global__ void k_init(float* __restrict__ lacc){
  if (threadIdx.x < 2) lacc[threadIdx.x] = 0.f;
}

// ---- K1: per-(b,j) FieldNet (unchanged)
__global__ __launch_bounds__(128) void k_fieldnet(
    const float* __restrict__ query, const float* __restrict__ mwl,
    const float* __restrict__ tm,    const float* __restrict__ W1,
    const float* __restrict__ b1,    const float* __restrict__ W2,
    const float* __restrict__ b2,    const float* __restrict__ cps,
    const float* __restrict__ cpm,   const float* __restrict__ cts,
    const float* __restrict__ ctm,   float* __restrict__ G)
{
  int bj = blockIdx.x;
  int b = bj / J_, l = bj % J_;
  __shared__ float h_s[3 + K_];
  __shared__ float hid_s[H_];
  __shared__ float rt_s[6];
  int t = threadIdx.x;
  if (t < K_) {
    float acc = 0.f;
    const float* tp = tm + (size_t)b * MK_ + t;
    const float* mp = mwl + l * MOT_;
    for (int j = 0; j < MOT_; j++){
      float w = mp[j]; w = w > 0.f ? w : 0.f;
      acc = fmaf(w, tp[j * K_], acc);
    }
    h_s[3 + t] = acc;
  } else if (t < K_ + 3) {
    h_s[t - K_] = query[(size_t)bj * 3 + (t - K_)];
  }
  __syncthreads();
  {
    float acc = b1[t];
    for (int i = 0; i < 3 + K_; i++) acc = fmaf(h_s[i], W1[i * H_ + t], acc);
    hid_s[t] = acc > 0.f ? acc : 0.f;
  }
  __syncthreads();
  if (t < 6){
    float acc = b2[t];
    for (int i = 0; i < H_; i++) acc = fmaf(hid_s[i], W2[i * 6 + t], acc);
    rt_s[t] = acc;
  }
  __syncthreads();
  if (t == 0){
    const float D2R = 0.017453292519943295f;
    float ax = fmaf(rt_s[0], cps[0], cpm[0]) * D2R;
    float ay = fmaf(rt_s[1], cps[1], cpm[1]) * D2R;
    float az = fmaf(rt_s[2], cps[2], cpm[2]) * D2R;
    float tx = fmaf(h_s[0] + rt_s[3], cts[0], ctm[0]);
    float ty = fmaf(h_s[1] + rt_s[4], cts[1], ctm[1]);
    float tz = fmaf(h_s[2] + rt_s[5], cts[2], ctm[2]);
    float sx, cx, sy, cy, sz, cz;
    sincosf(ax, &sx, &cx); sincosf(ay, &sy, &cy); sincosf(az, &sz, &cz);
    float* g = G + (size_t)bj * 12;
    g[0] = cz * cy; g[1] = cz * sy * sx - sz * cx; g[2]  = cz * sy * cx + sz * sx; g[3]  = tx;
    g[4] = sz * cy; g[5] = sz * sy * sx + cz * cx; g[6]  = sz * sy * cx - cz * sx; g[7]  = ty;
    g[8] = -sy;     g[9] = cy * sx;                g[10] = cy * cx;                g[11] = tz;
  }
}

// ---- K2a: transpose tm[64][6016] -> tm_t[6016][64] (for uniform row loads)
__global__ __launch_bounds__(256) void k_tmt(const float* __restrict__ tm,
                                             float* __restrict__ tm_t){
  __shared__ float ld[64][65];
  int t = threadIdx.x;
  int m0 = blockIdx.x * 64;
  int ml = t & 63, g = t >> 6;
  #pragma unroll
  for (int r = 0; r < 16; r++){
    int b = g * 16 + r;
    ld[ml][b] = tm[(size_t)b * MK_ + m0 + ml];
  }
  __syncthreads();
  int bl = t & 63;
  #pragma unroll
  for (int r = 0; r < 16; r++){
    int m = g * 16 + r;
    tm_t[(size_t)(m0 + m) * 64 + bl] = ld[m][bl];
  }
}

// ---- K2b: detailkey partial GEMM -> part[(sy*6+qt)][b*64+ql], NO atomics.
//           lane=q, acc over all 64 b; tm_t rows via wave-uniform scalar loads.
__global__ __launch_bounds__(256) void k_dkey(
    const float* __restrict__ tm_t, const float* __restrict__ Wd,
    float* __restrict__ part, int chunk)
{
  int t = threadIdx.x;
  int lane = t & 63;
  int wv = __builtin_amdgcn_readfirstlane(t >> 6);   // 0..3, pinned uniform
  int qt = blockIdx.x;
  int q = qt * 64 + lane;
  bool vq = q < Q_;
  int m0 = (blockIdx.y * 4 + wv) * chunk;
  float acc[64];
  #pragma unroll
  for (int i = 0; i < 64; i++) acc[i] = 0.f;
  for (int m = m0; m < m0 + chunk; m++){
    float wd = vq ? Wd[(size_t)m * Q_ + q] : 0.f;
    const float* tr = tm_t + (size_t)m * 64;         // uniform -> s_load_dwordx16
    #pragma unroll
    for (int i = 0; i < 64; i++)
      acc[i] = fmaf(tr[i], wd, acc[i]);
  }
  __shared__ float red[4 * 64 * 64];                 // 64 KB
  float* rw = red + wv * 4096;
  #pragma unroll
  for (int i = 0; i < 64; i++) rw[i * 64 + lane] = acc[i];   // conflict-free b32
  __syncthreads();
  float* pb = part + ((size_t)blockIdx.y * 6 + qt) * 4096;
  #pragma unroll
  for (int k = 0; k < 16; k++){
    int i = t + 256 * k;
    pb[i] = red[i] + red[4096 + i] + red[8192 + i] + red[12288 + i];
  }
}

// ---- K2c: reduce partials + bd -> dk_t[q*64+b]
__global__ __launch_bounds__(256) void k_dkred(
    const float* __restrict__ part, const float* __restrict__ bd,
    float* __restrict__ dk_t, int S)
{
  int j = blockIdx.x * 256 + threadIdx.x;            // j = b*340 + q
  if (j >= B_ * Q_) return;
  int b = j / Q_;
  int q = j - b * Q_;
  int qt = q >> 6, ql = q & 63;
  float s = bd[q];
  const float* pp = part + (size_t)qt * 4096 + b * 64 + ql;
  for (int sy = 0; sy < S; sy++) s += pp[(size_t)sy * 6 * 4096];
  dk_t[q * 64 + b] = s;
}

// ---- K3a: detail einsum (unchanged from round 3)
__global__ __launch_bounds__(512) void k_detail(
    const float* __restrict__ DPSD, const float* __restrict__ dk_t,
    const float* __restrict__ rstd, const float* __restrict__ rmean,
    float* __restrict__ out, float* __restrict__ lacc)
{
  int t = threadIdx.x;
  int lane = t & 63;
  int wv = __builtin_amdgcn_readfirstlane(t >> 6);   // 0..7
  int b0 = wv * 8;
  int e = blockIdx.x * 64 + lane;
  bool ve = e < NE_;
  const float* dkb = dk_t + b0;
  float acc[8];
  #pragma unroll
  for (int i = 0; i < 8; i++) acc[i] = 0.f;
  float sq = 0.f;
  for (int q = 0; q < Q_; q++){
    float d = ve ? DPSD[(size_t)q * NE_ + e] : 0.f;
    const float* dq = dkb + q * 64;                  // uniform -> s_load_dwordx8
    if (wv == 0) sq = fmaf(d, d, sq);
    #pragma unroll
    for (int i = 0; i < 8; i++) acc[i] = fmaf(dq[i], d, acc[i]);
  }
  if (ve){
    int x = e % 3;
    float s = rstd[x], m = rmean[x];
    #pragma unroll
    for (int i = 0; i < 8; i++)
      out[1 + (size_t)(b0 + i) * NE_ + e] = fmaf(acc[i], s, m);
  }
  if (wv == 0){
    #pragma unroll
    for (int off = 32; off; off >>= 1) sq += __shfl_xor(sq, off);
    if (lane == 0) atomicAdd(&lacc[1], sq);
  }
}

// ---- K3b: LBS skinning (unchanged from round 3)
__global__ __launch_bounds__(256) void k_skin(
    const float* __restrict__ G, const float* __restrict__ skin,
    const float* __restrict__ rest, const float* __restrict__ in_pc,
    float* __restrict__ out, float* __restrict__ lacc)
{
  __shared__ float G_s[4 * J_ * 12];
  int t = threadIdx.x;
  int p = blockIdx.x * 256 + t;
  int b0 = blockIdx.y * 4;
  for (int idx = t; idx < 4 * J_ * 12; idx += 256)
    G_s[idx] = G[(size_t)b0 * J_ * 12 + idx];
  bool vp = p < P_;
  float vx = 0.f, vy = 0.f, vz = 0.f;
  if (vp){ vx = rest[p * 3]; vy = rest[p * 3 + 1]; vz = rest[p * 3 + 2]; }
  float acc[4][3];
  #pragma unroll
  for (int bb = 0; bb < 4; bb++){ acc[bb][0] = acc[bb][1] = acc[bb][2] = 0.f; }
  __syncthreads();
  const float* wp = skin + (size_t)p * J_;
  for (int jc = 0; jc < 5; jc++){
    float wr[16];
    if (vp){
      #pragma unroll
      for (int r = 0; r < 4; r++){
        float4 u = *(const float4*)(wp + jc * 16 + r * 4);
        wr[r * 4 + 0] = u.x; wr[r * 4 + 1] = u.y;
        wr[r * 4 + 2] = u.z; wr[r * 4 + 3] = u.w;
      }
    } else {
      #pragma unroll
      for (int j = 0; j < 16; j++) wr[j] = 0.f;
    }
    int jbase = jc * 16;
    #pragma unroll
    for (int j = 0; j < 16; j++){
      #pragma unroll
      for (int bb = 0; bb < 4; bb++){
        const float* gp = G_s + (bb * J_ + jbase + j) * 12;
        float4 g0 = *(const float4*)(gp + 0);
        float4 g1 = *(const float4*)(gp + 4);
        float4 g2 = *(const float4*)(gp + 8);
        acc[bb][0] = fmaf(wr[j], fmaf(g0.x, vx, fmaf(g0.y, vy, fmaf(g0.z, vz, g0.w))), acc[bb][0]);
        acc[bb][1] = fmaf(wr[j], fmaf(g1.x, vx, fmaf(g1.y, vy, fmaf(g1.z, vz, g1.w))), acc[bb][1]);
        acc[bb][2] = fmaf(wr[j], fmaf(g2.x, vx, fmaf(g2.y, vy, fmaf(g2.z, vz, g2.w))), acc[bb][2]);
      }
    }
  }
  float lsum = 0.f;
  if (vp){
    #pragma unroll
    for (int bb = 0; bb < 4; bb++){
      size_t base = ((size_t)(b0 + bb) * P_ + p) * 3;
      #pragma unroll
      for (int x = 0; x < 3; x++){
        float v = acc[bb][x] + out[1 + base + x];
        lsum += fabsf(in_pc[base + x] - v);
        out[1 + base + x] = v;
      }
    }
  }
  #pragma unroll
  for (int off = 32; off; off >>= 1) lsum += __shfl_xor(lsum, off);
  if ((t & 63) == 0) atomicAdd(&lacc[0], lsum);
}

// ---- K4: finalize scalar loss
__global__ void k_finalize(const float* __restrict__ lacc, float* __restrict__ out){
  if (threadIdx.x == 0 && blockIdx.x == 0){
    float loss = lacc[0] * (1.f / 2356416.f) + 1e-4f * (lacc[1] * (1.f / 12518460.f));
    out[0] = loss;
  }
}

extern "C" void kernel_launch(void* const* d_in, const int* in_sizes, int n_in,
                              void* d_out, int out_size, void* d_ws, size_t ws_size,
                              hipStream_t stream){
  const float* in_pc = (const float*)d_in[0];
  const float* rest  = (const float*)d_in[2];
  const float* skin  = (const float*)d_in[3];
  const float* mwl   = (const float*)d_in[4];
  const float* query = (const float*)d_in[5];
  const float* cps   = (const float*)d_in[6];
  const float* cpm   = (const float*)d_in[7];
  const float* cts   = (const float*)d_in[8];
  const float* ctm   = (const float*)d_in[9];
  const float* W1    = (const float*)d_in[10];
  const float* b1    = (const float*)d_in[11];
  const float* W2    = (const float*)d_in[12];
  const float* b2    = (const float*)d_in[13];
  const float* tm    = (const float*)d_in[14];
  const float* Wd    = (const float*)d_in[15];
  const float* bd    = (const float*)d_in[16];
  const float* DPSD  = (const float*)d_in[17];
  const float* rstd  = (const float*)d_in[18];
  const float* rmean = (const float*)d_in[19];
  float* out = (float*)d_out;

  float* ws   = (float*)d_ws;
  float* G    = ws;                       // 61440 f32
  float* dk_t = ws + 61440;               // 21760 f32, [q][b]
  float* lacc = ws + 61440 + 21760;       // 2 f32 (+2 pad)
  float* tm_t = ws + 83204;               // 385024 f32
  float* part = ws + 83204 + 385024;      // S*6*4096 f32

  // S splits: 94 (9.2 MB partials) if ws allows, else 47
  size_t need94 = (size_t)(83204 + 385024 + 94 * 6 * 4096) * 4;
  int S = (ws_size >= need94) ? 94 : 47;
  int chunk = MK_ / (S * 4);              // 16 or 32 m per wave

  k_init    <<<1, 64, 0, stream>>>(lacc);
  k_fieldnet<<<B_ * J_, 128, 0, stream>>>(query, mwl, tm, W1, b1, W2, b2,
                                          cps, cpm, cts, ctm, G);
  k_tmt     <<<94, 256, 0, stream>>>(tm, tm_t);
  k_dkey    <<<dim3(6, S), 256, 0, stream>>>(tm_t, Wd, part, chunk);
  k_dkred   <<<85, 256, 0, stream>>>(part, bd, dk_t, S);
  k_detail  <<<576, 512, 0, stream>>>(DPSD, dk_t, rstd, rmean, out, lacc);
  k_skin    <<<dim3(48, 16), 256, 0, stream>>>(G, skin, rest, in_pc, out, lacc);
  k_finalize<<<1, 64, 0, stream>>>(lacc, out);
}

// Round 5
// 344.443 us; speedup vs baseline: 1.4749x; 1.0520x over previous
//
#include <hip/hip_runtime.h>

#define B_   64
#define P_   12273
#define J_   80
#define MOT_ 94
#define K_   64
#define H_   128
#define Q_   340      // NB*WN
#define NE_  36819    // P*3
#define MK_  6016     // MOT*K
#define PW_  12288    // padded P for w_t rows

// ---- K0: zero loss accumulators
__global__ void k_init(float* __restrict__ lacc){
  if (threadIdx.x < 2) lacc[threadIdx.x] = 0.f;
}

// ---- K1: per-(b,j) FieldNet (unchanged)
__global__ __launch_bounds__(128) void k_fieldnet(
    const float* __restrict__ query, const float* __restrict__ mwl,
    const float* __restrict__ tm,    const float* __restrict__ W1,
    const float* __restrict__ b1,    const float* __restrict__ W2,
    const float* __restrict__ b2,    const float* __restrict__ cps,
    const float* __restrict__ cpm,   const float* __restrict__ cts,
    const float* __restrict__ ctm,   float* __restrict__ G)
{
  int bj = blockIdx.x;
  int b = bj / J_, l = bj % J_;
  __shared__ float h_s[3 + K_];
  __shared__ float hid_s[H_];
  __shared__ float rt_s[6];
  int t = threadIdx.x;
  if (t < K_) {
    float acc = 0.f;
    const float* tp = tm + (size_t)b * MK_ + t;
    const float* mp = mwl + l * MOT_;
    for (int j = 0; j < MOT_; j++){
      float w = mp[j]; w = w > 0.f ? w : 0.f;
      acc = fmaf(w, tp[j * K_], acc);
    }
    h_s[3 + t] = acc;
  } else if (t < K_ + 3) {
    h_s[t - K_] = query[(size_t)bj * 3 + (t - K_)];
  }
  __syncthreads();
  {
    float acc = b1[t];
    for (int i = 0; i < 3 + K_; i++) acc = fmaf(h_s[i], W1[i * H_ + t], acc);
    hid_s[t] = acc > 0.f ? acc : 0.f;
  }
  __syncthreads();
  if (t < 6){
    float acc = b2[t];
    for (int i = 0; i < H_; i++) acc = fmaf(hid_s[i], W2[i * 6 + t], acc);
    rt_s[t] = acc;
  }
  __syncthreads();
  if (t == 0){
    const float D2R = 0.017453292519943295f;
    float ax = fmaf(rt_s[0], cps[0], cpm[0]) * D2R;
    float ay = fmaf(rt_s[1], cps[1], cpm[1]) * D2R;
    float az = fmaf(rt_s[2], cps[2], cpm[2]) * D2R;
    float tx = fmaf(h_s[0] + rt_s[3], cts[0], ctm[0]);
    float ty = fmaf(h_s[1] + rt_s[4], cts[1], ctm[1]);
    float tz = fmaf(h_s[2] + rt_s[5], cts[2], ctm[2]);
    float sx, cx, sy, cy, sz, cz;
    sincosf(ax, &sx, &cx); sincosf(ay, &sy, &cy); sincosf(az, &sz, &cz);
    float* g = G + (size_t)bj * 12;
    g[0] = cz * cy; g[1] = cz * sy * sx - sz * cx; g[2]  = cz * sy * cx + sz * sx; g[3]  = tx;
    g[4] = sz * cy; g[5] = sz * sy * sx + cz * cx; g[6]  = sz * sy * cx - cz * sx; g[7]  = ty;
    g[8] = -sy;     g[9] = cy * sx;                g[10] = cy * cx;                g[11] = tz;
  }
}

// ---- K2a: transpose tm[64][6016] -> tm_t[6016][64]
__global__ __launch_bounds__(256) void k_tmt(const float* __restrict__ tm,
                                             float* __restrict__ tm_t){
  __shared__ float ld[64][65];
  int t = threadIdx.x;
  int m0 = blockIdx.x * 64;
  int ml = t & 63, g = t >> 6;
  #pragma unroll
  for (int r = 0; r < 16; r++){
    int b = g * 16 + r;
    ld[ml][b] = tm[(size_t)b * MK_ + m0 + ml];
  }
  __syncthreads();
  int bl = t & 63;
  #pragma unroll
  for (int r = 0; r < 16; r++){
    int m = g * 16 + r;
    tm_t[(size_t)(m0 + m) * 64 + bl] = ld[m][bl];
  }
}

// ---- K2a': transpose skin[12273][80] -> w_t[80][12288] (zero-padded p)
__global__ __launch_bounds__(256) void k_wt(const float* __restrict__ skin,
                                            float* __restrict__ w_t){
  __shared__ float ld[80][65];
  int t = threadIdx.x;
  int p0 = blockIdx.x * 64;
  #pragma unroll
  for (int k = 0; k < 20; k++){
    int idx = k * 256 + t;
    int pl = idx / 80, j = idx - pl * 80;
    int p = p0 + pl;
    ld[j][pl] = (p < P_) ? skin[(size_t)p * J_ + j] : 0.f;
  }
  __syncthreads();
  #pragma unroll
  for (int k = 0; k < 20; k++){
    int idx = k * 256 + t;
    int j = idx >> 6, pl = idx & 63;
    w_t[(size_t)j * PW_ + p0 + pl] = ld[j][pl];
  }
}

// ---- K2b: detailkey partial GEMM (unchanged from round 4)
__global__ __launch_bounds__(256) void k_dkey(
    const float* __restrict__ tm_t, const float* __restrict__ Wd,
    float* __restrict__ part, int chunk)
{
  int t = threadIdx.x;
  int lane = t & 63;
  int wv = __builtin_amdgcn_readfirstlane(t >> 6);
  int qt = blockIdx.x;
  int q = qt * 64 + lane;
  bool vq = q < Q_;
  int m0 = (blockIdx.y * 4 + wv) * chunk;
  float acc[64];
  #pragma unroll
  for (int i = 0; i < 64; i++) acc[i] = 0.f;
  for (int m = m0; m < m0 + chunk; m++){
    float wd = vq ? Wd[(size_t)m * Q_ + q] : 0.f;
    const float* tr = tm_t + (size_t)m * 64;
    #pragma unroll
    for (int i = 0; i < 64; i++)
      acc[i] = fmaf(tr[i], wd, acc[i]);
  }
  __shared__ float red[4 * 64 * 64];
  float* rw = red + wv * 4096;
  #pragma unroll
  for (int i = 0; i < 64; i++) rw[i * 64 + lane] = acc[i];
  __syncthreads();
  float* pb = part + ((size_t)blockIdx.y * 6 + qt) * 4096;
  #pragma unroll
  for (int k = 0; k < 16; k++){
    int i = t + 256 * k;
    pb[i] = red[i] + red[4096 + i] + red[8192 + i] + red[12288 + i];
  }
}

// ---- K2c: reduce partials + bd -> dk_t[q*64+b]
__global__ __launch_bounds__(256) void k_dkred(
    const float* __restrict__ part, const float* __restrict__ bd,
    float* __restrict__ dk_t, int S)
{
  int j = blockIdx.x * 256 + threadIdx.x;
  if (j >= B_ * Q_) return;
  int b = j / Q_;
  int q = j - b * Q_;
  int qt = q >> 6, ql = q & 63;
  float s = bd[q];
  const float* pp = part + (size_t)qt * 4096 + b * 64 + ql;
  for (int sy = 0; sy < S; sy++) s += pp[(size_t)sy * 6 * 4096];
  dk_t[q * 64 + b] = s;
}

// ---- K3a: detail einsum (unchanged from round 4)
__global__ __launch_bounds__(512) void k_detail(
    const float* __restrict__ DPSD, const float* __restrict__ dk_t,
    const float* __restrict__ rstd, const float* __restrict__ rmean,
    float* __restrict__ out, float* __restrict__ lacc)
{
  int t = threadIdx.x;
  int lane = t & 63;
  int wv = __builtin_amdgcn_readfirstlane(t >> 6);   // 0..7
  int b0 = wv * 8;
  int e = blockIdx.x * 64 + lane;
  bool ve = e < NE_;
  const float* dkb = dk_t + b0;
  float acc[8];
  #pragma unroll
  for (int i = 0; i < 8; i++) acc[i] = 0.f;
  float sq = 0.f;
  for (int q = 0; q < Q_; q++){
    float d = ve ? DPSD[(size_t)q * NE_ + e] : 0.f;
    const float* dq = dkb + q * 64;                  // uniform -> s_load
    if (wv == 0) sq = fmaf(d, d, sq);
    #pragma unroll
    for (int i = 0; i < 8; i++) acc[i] = fmaf(dq[i], d, acc[i]);
  }
  if (ve){
    int x = e % 3;
    float s = rstd[x], m = rmean[x];
    #pragma unroll
    for (int i = 0; i < 8; i++)
      out[1 + (size_t)(b0 + i) * NE_ + e] = fmaf(acc[i], s, m);
  }
  if (wv == 0){
    #pragma unroll
    for (int off = 32; off; off >>= 1) sq += __shfl_xor(sq, off);
    if (lane == 0) atomicAdd(&lacc[1], sq);
  }
}

// ---- K3b: LBS skinning, rewritten: wave = 64 p-lanes x 2 batches.
//           G via wave-uniform scalar loads (no LDS), w via coalesced w_t.
__global__ __launch_bounds__(256) void k_skin(
    const float* __restrict__ G, const float* __restrict__ w_t,
    const float* __restrict__ rest, const float* __restrict__ in_pc,
    float* __restrict__ out, float* __restrict__ lacc)
{
  int t = threadIdx.x;
  int lane = t & 63;
  int wv = __builtin_amdgcn_readfirstlane(t >> 6);   // 0..3
  int p  = blockIdx.x * 64 + lane;                   // < PW_, w_t padded
  int bA = blockIdx.y * 8 + wv * 2;
  const float* gA = G + (size_t)bA * J_ * 12;
  const float* gB = gA + (size_t)J_ * 12;
  float accA[12], accB[12];
  #pragma unroll
  for (int c = 0; c < 12; c++){ accA[c] = 0.f; accB[c] = 0.f; }
  const float* wp = w_t + p;
  #pragma unroll 4
  for (int j = 0; j < J_; j++){
    float w = wp[(size_t)j * PW_];
    const float* ga = gA + j * 12;                   // uniform -> s_load
    const float* gb = gB + j * 12;
    #pragma unroll
    for (int c = 0; c < 12; c++){
      accA[c] = fmaf(w, ga[c], accA[c]);
      accB[c] = fmaf(w, gb[c], accB[c]);
    }
  }
  bool vp = p < P_;
  float vx = 0.f, vy = 0.f, vz = 0.f;
  if (vp){ vx = rest[p * 3]; vy = rest[p * 3 + 1]; vz = rest[p * 3 + 2]; }
  float lsum = 0.f;
  if (vp){
    size_t baseA = ((size_t)bA * P_ + p) * 3;
    size_t baseB = baseA + (size_t)P_ * 3;
    #pragma unroll
    for (int x = 0; x < 3; x++){
      float v = fmaf(accA[x*4+0], vx, fmaf(accA[x*4+1], vy, fmaf(accA[x*4+2], vz, accA[x*4+3])));
      v += out[1 + baseA + x];
      lsum += fabsf(in_pc[baseA + x] - v);
      out[1 + baseA + x] = v;
    }
    #pragma unroll
    for (int x = 0; x < 3; x++){
      float v = fmaf(accB[x*4+0], vx, fmaf(accB[x*4+1], vy, fmaf(accB[x*4+2], vz, accB[x*4+3])));
      v += out[1 + baseB + x];
      lsum += fabsf(in_pc[baseB + x] - v);
      out[1 + baseB + x] = v;
    }
  }
  #pragma unroll
  for (int off = 32; off; off >>= 1) lsum += __shfl_xor(lsum, off);
  __shared__ float red[4];
  if (lane == 0) red[wv] = lsum;
  __syncthreads();
  if (t == 0) atomicAdd(&lacc[0], red[0] + red[1] + red[2] + red[3]);
}

// ---- K4: finalize scalar loss
__global__ void k_finalize(const float* __restrict__ lacc, float* __restrict__ out){
  if (threadIdx.x == 0 && blockIdx.x == 0){
    float loss = lacc[0] * (1.f / 2356416.f) + 1e-4f * (lacc[1] * (1.f / 12518460.f));
    out[0] = loss;
  }
}

extern "C" void kernel_launch(void* const* d_in, const int* in_sizes, int n_in,
                              void* d_out, int out_size, void* d_ws, size_t ws_size,
                              hipStream_t stream){
  const float* in_pc = (const float*)d_in[0];
  const float* rest  = (const float*)d_in[2];
  const float* skin  = (const float*)d_in[3];
  const float* mwl   = (const float*)d_in[4];
  const float* query = (const float*)d_in[5];
  const float* cps   = (const float*)d_in[6];
  const float* cpm   = (const float*)d_in[7];
  const float* cts   = (const float*)d_in[8];
  const float* ctm   = (const float*)d_in[9];
  const float* W1    = (const float*)d_in[10];
  const float* b1    = (const float*)d_in[11];
  const float* W2    = (const float*)d_in[12];
  const float* b2    = (const float*)d_in[13];
  const float* tm    = (const float*)d_in[14];
  const float* Wd    = (const float*)d_in[15];
  const float* bd    = (const float*)d_in[16];
  const float* DPSD  = (const float*)d_in[17];
  const float* rstd  = (const float*)d_in[18];
  const float* rmean = (const float*)d_in[19];
  float* out = (float*)d_out;

  float* ws   = (float*)d_ws;
  float* G    = ws;                        // 61440
  float* dk_t = ws + 61440;                // 21760
  float* lacc = ws + 61440 + 21760;        // 4
  float* tm_t = ws + 83204;                // 385024
  float* w_t  = ws + 83204 + 385024;       // 80*12288 = 983040
  float* part = ws + 83204 + 385024 + 983040;  // S*6*4096

  size_t fixed = 83204 + 385024 + 983040;
  int S = 16;
  if (ws_size >= (fixed + (size_t)94 * 24576) * 4) S = 94;
  else if (ws_size >= (fixed + (size_t)47 * 24576) * 4) S = 47;
  int chunk = MK_ / (S * 4);

  k_init    <<<1, 64, 0, stream>>>(lacc);
  k_fieldnet<<<B_ * J_, 128, 0, stream>>>(query, mwl, tm, W1, b1, W2, b2,
                                          cps, cpm, cts, ctm, G);
  k_tmt     <<<94, 256, 0, stream>>>(tm, tm_t);
  k_wt      <<<192, 256, 0, stream>>>(skin, w_t);
  k_dkey    <<<dim3(6, S), 256, 0, stream>>>(tm_t, Wd, part, chunk);
  k_dkred   <<<85, 256, 0, stream>>>(part, bd, dk_t, S);
  k_detail  <<<576, 512, 0, stream>>>(DPSD, dk_t, rstd, rmean, out, lacc);
  k_skin    <<<dim3(192, 8), 256, 0, stream>>>(G, w_t, rest, in_pc, out, lacc);
  k_finalize<<<1, 64, 0, stream>>>(lacc, out);
}

// Round 6
// 283.261 us; speedup vs baseline: 1.7935x; 1.2160x over previous
//
#include <hip/hip_runtime.h>

#define B_   64
#define P_   12273
#define J_   80
#define MOT_ 94
#define K_   64
#define H_   128
#define Q_   340      // NB*WN
#define NE_  36819    // P*3
#define MK_  6016     // MOT*K
#define PW_  12288    // padded P for w_t rows

typedef float v4f  __attribute__((ext_vector_type(4)));
typedef float v8f  __attribute__((ext_vector_type(8)));
typedef float v16f __attribute__((ext_vector_type(16)));
#define AS4 __attribute__((address_space(4)))

// Force scalar (s_load) path: constant-AS pointer built from a wave-uniform address.
__device__ __forceinline__ const AS4 float* unif(const float* p){
  return (const AS4 float*)(unsigned long long)p;
}
__device__ __forceinline__ const AS4 v4f* univ4(const float* p){
  return (const AS4 v4f*)(unsigned long long)p;
}
__device__ __forceinline__ const AS4 v8f* univ8(const float* p){
  return (const AS4 v8f*)(unsigned long long)p;
}
__device__ __forceinline__ const AS4 v16f* univ16(const float* p){
  return (const AS4 v16f*)(unsigned long long)p;
}

// ---- K1 "prep": fused fieldnet (blocks 0..1279, one wave per (b,j)) +
//      tm transpose (1280..1373) + skin transpose (1374..1565) + lacc init (1566)
__global__ __launch_bounds__(256) void k_prep(
    const float* __restrict__ query, const float* __restrict__ mwl,
    const float* __restrict__ tm,    const float* __restrict__ W1,
    const float* __restrict__ b1,    const float* __restrict__ W2,
    const float* __restrict__ b2,    const float* __restrict__ cps,
    const float* __restrict__ cpm,   const float* __restrict__ cts,
    const float* __restrict__ ctm,   const float* __restrict__ skin,
    float* __restrict__ G,           float* __restrict__ tm_t,
    float* __restrict__ w_t,         float* __restrict__ lacc)
{
  __shared__ float smem[80 * 65];
  int blk = blockIdx.x;
  int t = threadIdx.x;
  if (blk < 1280){
    // ---------- fieldnet: wave wv handles bj = blk*4+wv ----------
    int lane = t & 63;
    int wid = __builtin_amdgcn_readfirstlane(t >> 6);
    int bj = blk * 4 + wid;
    int b = bj / J_, l = bj - b * J_;
    float* hs = smem + wid * 80;
    // phase A: field_input[k=lane] = sum_j relu(mwl[l][j]) * tm[b][j*64+k]
    float acc = 0.f;
    const AS4 float* mp = unif(mwl + l * MOT_);
    const float* tp = tm + (size_t)b * MK_ + lane;
    #pragma unroll 2
    for (int j = 0; j < MOT_; j++){
      float w = mp[j]; w = w > 0.f ? w : 0.f;
      acc = fmaf(w, tp[j * K_], acc);
    }
    hs[3 + lane] = acc;
    if (lane < 3) hs[lane] = query[(size_t)bj * 3 + lane];
    __syncthreads();
    // phase B: hidden = relu(h @ W1 + b1); lane owns units lane, lane+64
    float a1 = b1[lane], a2 = b1[lane + 64];
    for (int i = 0; i < 3 + K_; i++){
      float hv = hs[i];
      a1 = fmaf(hv, W1[i * H_ + lane], a1);
      a2 = fmaf(hv, W1[i * H_ + 64 + lane], a2);
    }
    a1 = a1 > 0.f ? a1 : 0.f;
    a2 = a2 > 0.f ? a2 : 0.f;
    // phase C: rt[o] = sum_i hid[i]*W2[i][o] + b2[o], wave butterfly reduce
    const AS4 float* b2c = unif(b2);
    float rt[6];
    #pragma unroll
    for (int o = 0; o < 6; o++){
      float po = fmaf(a1, W2[lane * 6 + o], a2 * W2[(lane + 64) * 6 + o]);
      #pragma unroll
      for (int off = 32; off; off >>= 1) po += __shfl_xor(po, off);
      rt[o] = po + b2c[o];
    }
    const float D2R = 0.017453292519943295f;
    float ax = fmaf(rt[0], cps[0], cpm[0]) * D2R;
    float ay = fmaf(rt[1], cps[1], cpm[1]) * D2R;
    float az = fmaf(rt[2], cps[2], cpm[2]) * D2R;
    float tx = fmaf(hs[0] + rt[3], cts[0], ctm[0]);
    float ty = fmaf(hs[1] + rt[4], cts[1], ctm[1]);
    float tz = fmaf(hs[2] + rt[5], cts[2], ctm[2]);
    float sx, cx, sy, cy, sz, cz;
    sincosf(ax, &sx, &cx); sincosf(ay, &sy, &cy); sincosf(az, &sz, &cz);
    if (lane == 0){
      float4 r0 = make_float4(cz*cy, cz*sy*sx - sz*cx, cz*sy*cx + sz*sx, tx);
      float4 r1 = make_float4(sz*cy, sz*sy*sx + cz*cx, sz*sy*cx - cz*sx, ty);
      float4 r2 = make_float4(-sy,   cy*sx,            cy*cx,            tz);
      float4* g = (float4*)(G + (size_t)bj * 12);
      g[0] = r0; g[1] = r1; g[2] = r2;
    }
  } else if (blk < 1374){
    // ---------- tm transpose: tm[64][6016] -> tm_t[6016][64] ----------
    int m0 = (blk - 1280) * 64;
    int ml = t & 63, g = t >> 6;
    #pragma unroll
    for (int r = 0; r < 16; r++){
      int b = g * 16 + r;
      smem[ml * 65 + b] = tm[(size_t)b * MK_ + m0 + ml];
    }
    __syncthreads();
    int bl = t & 63;
    #pragma unroll
    for (int r = 0; r < 16; r++){
      int m = g * 16 + r;
      tm_t[(size_t)(m0 + m) * 64 + bl] = smem[m * 65 + bl];
    }
  } else if (blk < 1566){
    // ---------- skin transpose: skin[12273][80] -> w_t[80][12288] ----------
    int p0 = (blk - 1374) * 64;
    #pragma unroll
    for (int k = 0; k < 20; k++){
      int idx = k * 256 + t;
      int pl = idx / 80, j = idx - pl * 80;
      int p = p0 + pl;
      smem[j * 65 + pl] = (p < P_) ? skin[(size_t)p * J_ + j] : 0.f;
    }
    __syncthreads();
    #pragma unroll
    for (int k = 0; k < 20; k++){
      int idx = k * 256 + t;
      int j = idx >> 6, pl = idx & 63;
      w_t[(size_t)j * PW_ + p0 + pl] = smem[j * 65 + pl];
    }
  } else {
    if (t < 2) lacc[t] = 0.f;
  }
}

// ---- K2: detailkey partial GEMM -> part[(sy*6+qt)][b*64+ql], no atomics.
//          tm_t rows via forced s_load_dwordx16; Wd coalesced, read once.
__global__ __launch_bounds__(256) void k_dkey(
    const float* __restrict__ tm_t, const float* __restrict__ Wd,
    float* __restrict__ part, int chunk)
{
  int t = threadIdx.x;
  int lane = t & 63;
  int wid = __builtin_amdgcn_readfirstlane(t >> 6);
  int qt = blockIdx.x;
  int q = qt * 64 + lane;
  bool vq = q < Q_;
  int m0 = (blockIdx.y * 4 + wid) * chunk;
  float acc[64];
  #pragma unroll
  for (int i = 0; i < 64; i++) acc[i] = 0.f;
  const AS4 v16f* tr = univ16(tm_t);
  for (int m = m0; m < m0 + chunk; m++){
    float wd = vq ? Wd[(size_t)m * Q_ + q] : 0.f;
    v16f t0 = tr[m * 4 + 0];
    v16f t1 = tr[m * 4 + 1];
    v16f t2 = tr[m * 4 + 2];
    v16f t3 = tr[m * 4 + 3];
    #pragma unroll
    for (int i = 0; i < 16; i++){
      acc[i]      = fmaf(t0[i], wd, acc[i]);
      acc[16 + i] = fmaf(t1[i], wd, acc[16 + i]);
      acc[32 + i] = fmaf(t2[i], wd, acc[32 + i]);
      acc[48 + i] = fmaf(t3[i], wd, acc[48 + i]);
    }
  }
  __shared__ float red[4 * 64 * 64];
  float* rw = red + wid * 4096;
  #pragma unroll
  for (int i = 0; i < 64; i++) rw[i * 64 + lane] = acc[i];
  __syncthreads();
  float* pb = part + ((size_t)blockIdx.y * 6 + qt) * 4096;
  #pragma unroll
  for (int k = 0; k < 16; k++){
    int i = t + 256 * k;
    pb[i] = red[i] + red[4096 + i] + red[8192 + i] + red[12288 + i];
  }
}

// ---- K3: reduce partials + bd -> dk_t[q*64+b]; 8 independent load streams
__global__ __launch_bounds__(256) void k_dkred(
    const float* __restrict__ part, const float* __restrict__ bd,
    float* __restrict__ dk_t, int S)
{
  int j = blockIdx.x * 256 + threadIdx.x;
  if (j >= B_ * Q_) return;
  int b = j / Q_;
  int q = j - b * Q_;
  int qt = q >> 6, ql = q & 63;
  const float* pp = part + (size_t)qt * 4096 + b * 64 + ql;
  const size_t ST = 6 * 4096;
  float s0 = 0.f, s1 = 0.f, s2 = 0.f, s3 = 0.f;
  float s4 = 0.f, s5 = 0.f, s6 = 0.f, s7 = 0.f;
  int sy = 0;
  for (; sy + 8 <= S; sy += 8){
    s0 += pp[(sy + 0) * ST]; s1 += pp[(sy + 1) * ST];
    s2 += pp[(sy + 2) * ST]; s3 += pp[(sy + 3) * ST];
    s4 += pp[(sy + 4) * ST]; s5 += pp[(sy + 5) * ST];
    s6 += pp[(sy + 6) * ST]; s7 += pp[(sy + 7) * ST];
  }
  for (; sy < S; sy++) s0 += pp[(size_t)sy * ST];
  dk_t[q * 64 + b] = bd[q] + (((s0 + s1) + (s2 + s3)) + ((s4 + s5) + (s6 + s7)));
}

// ---- K4: detail einsum; dk rows via forced s_load_dwordx8; q-loop unrolled x4
__global__ __launch_bounds__(512) void k_detail(
    const float* __restrict__ DPSD, const float* __restrict__ dk_t,
    const float* __restrict__ rstd, const float* __restrict__ rmean,
    float* __restrict__ out, float* __restrict__ lacc)
{
  int t = threadIdx.x;
  int lane = t & 63;
  int wid = __builtin_amdgcn_readfirstlane(t >> 6);  // 0..7
  int b0 = wid * 8;
  int e = blockIdx.x * 64 + lane;
  bool ve = e < NE_;
  const AS4 v8f* dkv = univ8(dk_t + b0);             // row q at v8-index q*8/8 = q... (q*64 floats)
  float acc[8];
  #pragma unroll
  for (int i = 0; i < 8; i++) acc[i] = 0.f;
  float sq = 0.f;
  const float* Dp = DPSD + e;
  for (int q0 = 0; q0 < Q_; q0 += 4){
    float d0 = ve ? Dp[(size_t)(q0 + 0) * NE_] : 0.f;
    float d1 = ve ? Dp[(size_t)(q0 + 1) * NE_] : 0.f;
    float d2 = ve ? Dp[(size_t)(q0 + 2) * NE_] : 0.f;
    float d3 = ve ? Dp[(size_t)(q0 + 3) * NE_] : 0.f;
    v8f r0 = dkv[(q0 + 0) * 8];
    v8f r1 = dkv[(q0 + 1) * 8];
    v8f r2 = dkv[(q0 + 2) * 8];
    v8f r3 = dkv[(q0 + 3) * 8];
    if (wid == 0){
      sq = fmaf(d0, d0, sq); sq = fmaf(d1, d1, sq);
      sq = fmaf(d2, d2, sq); sq = fmaf(d3, d3, sq);
    }
    #pragma unroll
    for (int i = 0; i < 8; i++){
      acc[i] = fmaf(r0[i], d0, acc[i]);
      acc[i] = fmaf(r1[i], d1, acc[i]);
      acc[i] = fmaf(r2[i], d2, acc[i]);
      acc[i] = fmaf(r3[i], d3, acc[i]);
    }
  }
  if (ve){
    int x = e % 3;
    float s = rstd[x], m = rmean[x];
    #pragma unroll
    for (int i = 0; i < 8; i++)
      out[1 + (size_t)(b0 + i) * NE_ + e] = fmaf(acc[i], s, m);
  }
  if (wid == 0){
    #pragma unroll
    for (int off = 32; off; off >>= 1) sq += __shfl_xor(sq, off);
    if (lane == 0) atomicAdd(&lacc[1], sq);
  }
}

// ---- K5: LBS skinning; G rows via forced s_load (v4); w via coalesced w_t
__global__ __launch_bounds__(256) void k_skin(
    const float* __restrict__ G, const float* __restrict__ w_t,
    const float* __restrict__ rest, const float* __restrict__ in_pc,
    float* __restrict__ out, float* __restrict__ lacc)
{
  int t = threadIdx.x;
  int lane = t & 63;
  int wid = __builtin_amdgcn_readfirstlane(t >> 6);  // 0..3
  int p  = blockIdx.x * 64 + lane;
  int bA = blockIdx.y * 8 + wid * 2;
  const AS4 v4f* gA = univ4(G + (size_t)bA * J_ * 12);   // row j: v4-index j*3
  const AS4 v4f* gB = univ4(G + ((size_t)bA + 1) * J_ * 12);
  float accA[12], accB[12];
  #pragma unroll
  for (int c = 0; c < 12; c++){ accA[c] = 0.f; accB[c] = 0.f; }
  const float* wp = w_t + p;
  #pragma unroll 4
  for (int j = 0; j < J_; j++){
    float w = wp[(size_t)j * PW_];
    v4f a0 = gA[j * 3 + 0], a1 = gA[j * 3 + 1], a2 = gA[j * 3 + 2];
    v4f c0 = gB[j * 3 + 0], c1 = gB[j * 3 + 1], c2 = gB[j * 3 + 2];
    #pragma unroll
    for (int c = 0; c < 4; c++){
      accA[c]     = fmaf(w, a0[c], accA[c]);
      accA[4 + c] = fmaf(w, a1[c], accA[4 + c]);
      accA[8 + c] = fmaf(w, a2[c], accA[8 + c]);
      accB[c]     = fmaf(w, c0[c], accB[c]);
      accB[4 + c] = fmaf(w, c1[c], accB[4 + c]);
      accB[8 + c] = fmaf(w, c2[c], accB[8 + c]);
    }
  }
  bool vp = p < P_;
  float vx = 0.f, vy = 0.f, vz = 0.f;
  if (vp){ vx = rest[p * 3]; vy = rest[p * 3 + 1]; vz = rest[p * 3 + 2]; }
  float lsum = 0.f;
  if (vp){
    size_t baseA = ((size_t)bA * P_ + p) * 3;
    size_t baseB = baseA + (size_t)P_ * 3;
    #pragma unroll
    for (int x = 0; x < 3; x++){
      float v = fmaf(accA[x*4+0], vx, fmaf(accA[x*4+1], vy, fmaf(accA[x*4+2], vz, accA[x*4+3])));
      v += out[1 + baseA + x];
      lsum += fabsf(in_pc[baseA + x] - v);
      out[1 + baseA + x] = v;
    }
    #pragma unroll
    for (int x = 0; x < 3; x++){
      float v = fmaf(accB[x*4+0], vx, fmaf(accB[x*4+1], vy, fmaf(accB[x*4+2], vz, accB[x*4+3])));
      v += out[1 + baseB + x];
      lsum += fabsf(in_pc[baseB + x] - v);
      out[1 + baseB + x] = v;
    }
  }
  #pragma unroll
  for (int off = 32; off; off >>= 1) lsum += __shfl_xor(lsum, off);
  __shared__ float red[4];
  if (lane == 0) red[wid] = lsum;
  __syncthreads();
  if (t == 0) atomicAdd(&lacc[0], red[0] + red[1] + red[2] + red[3]);
}

// ---- K6: finalize scalar loss
__global__ void k_finalize(const float* __restrict__ lacc, float* __restrict__ out){
  if (threadIdx.x == 0 && blockIdx.x == 0){
    float loss = lacc[0] * (1.f / 2356416.f) + 1e-4f * (lacc[1] * (1.f / 12518460.f));
    out[0] = loss;
  }
}

extern "C" void kernel_launch(void* const* d_in, const int* in_sizes, int n_in,
                              void* d_out, int out_size, void* d_ws, size_t ws_size,
                              hipStream_t stream){
  const float* in_pc = (const float*)d_in[0];
  const float* rest  = (const float*)d_in[2];
  const float* skin  = (const float*)d_in[3];
  const float* mwl   = (const float*)d_in[4];
  const float* query = (const float*)d_in[5];
  const float* cps   = (const float*)d_in[6];
  const float* cpm   = (const float*)d_in[7];
  const float* cts   = (const float*)d_in[8];
  const float* ctm   = (const float*)d_in[9];
  const float* W1    = (const float*)d_in[10];
  const float* b1    = (const float*)d_in[11];
  const float* W2    = (const float*)d_in[12];
  const float* b2    = (const float*)d_in[13];
  const float* tm    = (const float*)d_in[14];
  const float* Wd    = (const float*)d_in[15];
  const float* bd    = (const float*)d_in[16];
  const float* DPSD  = (const float*)d_in[17];
  const float* rstd  = (const float*)d_in[18];
  const float* rmean = (const float*)d_in[19];
  float* out = (float*)d_out;

  float* ws   = (float*)d_ws;
  float* G    = ws;                        // 61440
  float* dk_t = ws + 61440;                // 21760
  float* lacc = ws + 61440 + 21760;        // 4
  float* tm_t = ws + 83204;                // 385024
  float* w_t  = ws + 83204 + 385024;       // 983040
  float* part = ws + 83204 + 385024 + 983040;  // S*6*4096

  size_t fixed = 83204 + 385024 + 983040;
  int S = 16;
  if (ws_size >= (fixed + (size_t)94 * 24576) * 4) S = 94;
  else if (ws_size >= (fixed + (size_t)47 * 24576) * 4) S = 47;
  int chunk = MK_ / (S * 4);

  k_prep    <<<1567, 256, 0, stream>>>(query, mwl, tm, W1, b1, W2, b2,
                                       cps, cpm, cts, ctm, skin,
                                       G, tm_t, w_t, lacc);
  k_dkey    <<<dim3(6, S), 256, 0, stream>>>(tm_t, Wd, part, chunk);
  k_dkred   <<<85, 256, 0, stream>>>(part, bd, dk_t, S);
  k_detail  <<<576, 512, 0, stream>>>(DPSD, dk_t, rstd, rmean, out, lacc);
  k_skin    <<<dim3(192, 8), 256, 0, stream>>>(G, w_t, rest, in_pc, out, lacc);
  k_finalize<<<1, 64, 0, stream>>>(lacc, out);
}

// Round 7
// 268.445 us; speedup vs baseline: 1.8925x; 1.0552x over previous
//
#include <hip/hip_runtime.h>

#define B_   64
#define P_   12273
#define J_   80
#define MOT_ 94
#define K_   64
#define H_   128
#define Q_   340      // NB*WN
#define NE_  36819    // P*3
#define MK_  6016     // MOT*K
#define PW_  12288    // padded P for w_t rows

typedef float v4f  __attribute__((ext_vector_type(4)));
typedef float v8f  __attribute__((ext_vector_type(8)));
typedef float v16f __attribute__((ext_vector_type(16)));
#define AS4 __attribute__((address_space(4)))

__device__ __forceinline__ const AS4 float* unif(const float* p){
  return (const AS4 float*)(unsigned long long)p;
}
__device__ __forceinline__ const AS4 v4f* univ4(const float* p){
  return (const AS4 v4f*)(unsigned long long)p;
}
__device__ __forceinline__ const AS4 v8f* univ8(const float* p){
  return (const AS4 v8f*)(unsigned long long)p;
}
__device__ __forceinline__ const AS4 v16f* univ16(const float* p){
  return (const AS4 v16f*)(unsigned long long)p;
}

// ---- K1 "prep": fused fieldnet + tm transpose + skin transpose + lacc init
__global__ __launch_bounds__(256) void k_prep(
    const float* __restrict__ query, const float* __restrict__ mwl,
    const float* __restrict__ tm,    const float* __restrict__ W1,
    const float* __restrict__ b1,    const float* __restrict__ W2,
    const float* __restrict__ b2,    const float* __restrict__ cps,
    const float* __restrict__ cpm,   const float* __restrict__ cts,
    const float* __restrict__ ctm,   const float* __restrict__ skin,
    float* __restrict__ G,           float* __restrict__ tm_t,
    float* __restrict__ w_t,         float* __restrict__ lacc)
{
  __shared__ float smem[80 * 65];
  int blk = blockIdx.x;
  int t = threadIdx.x;
  if (blk < 1280){
    int lane = t & 63;
    int wid = __builtin_amdgcn_readfirstlane(t >> 6);
    int bj = blk * 4 + wid;
    int b = bj / J_, l = bj - b * J_;
    float* hs = smem + wid * 80;
    float acc = 0.f;
    const AS4 float* mp = unif(mwl + l * MOT_);
    const float* tp = tm + (size_t)b * MK_ + lane;
    #pragma unroll 2
    for (int j = 0; j < MOT_; j++){
      float w = mp[j]; w = w > 0.f ? w : 0.f;
      acc = fmaf(w, tp[j * K_], acc);
    }
    hs[3 + lane] = acc;
    if (lane < 3) hs[lane] = query[(size_t)bj * 3 + lane];
    __syncthreads();
    float a1 = b1[lane], a2 = b1[lane + 64];
    for (int i = 0; i < 3 + K_; i++){
      float hv = hs[i];
      a1 = fmaf(hv, W1[i * H_ + lane], a1);
      a2 = fmaf(hv, W1[i * H_ + 64 + lane], a2);
    }
    a1 = a1 > 0.f ? a1 : 0.f;
    a2 = a2 > 0.f ? a2 : 0.f;
    const AS4 float* b2c = unif(b2);
    float rt[6];
    #pragma unroll
    for (int o = 0; o < 6; o++){
      float po = fmaf(a1, W2[lane * 6 + o], a2 * W2[(lane + 64) * 6 + o]);
      #pragma unroll
      for (int off = 32; off; off >>= 1) po += __shfl_xor(po, off);
      rt[o] = po + b2c[o];
    }
    const float D2R = 0.017453292519943295f;
    float ax = fmaf(rt[0], cps[0], cpm[0]) * D2R;
    float ay = fmaf(rt[1], cps[1], cpm[1]) * D2R;
    float az = fmaf(rt[2], cps[2], cpm[2]) * D2R;
    float tx = fmaf(hs[0] + rt[3], cts[0], ctm[0]);
    float ty = fmaf(hs[1] + rt[4], cts[1], ctm[1]);
    float tz = fmaf(hs[2] + rt[5], cts[2], ctm[2]);
    float sx, cx, sy, cy, sz, cz;
    sincosf(ax, &sx, &cx); sincosf(ay, &sy, &cy); sincosf(az, &sz, &cz);
    if (lane == 0){
      float4 r0 = make_float4(cz*cy, cz*sy*sx - sz*cx, cz*sy*cx + sz*sx, tx);
      float4 r1 = make_float4(sz*cy, sz*sy*sx + cz*cx, sz*sy*cx - cz*sx, ty);
      float4 r2 = make_float4(-sy,   cy*sx,            cy*cx,            tz);
      float4* g = (float4*)(G + (size_t)bj * 12);
      g[0] = r0; g[1] = r1; g[2] = r2;
    }
  } else if (blk < 1374){
    int m0 = (blk - 1280) * 64;
    int ml = t & 63, g = t >> 6;
    #pragma unroll
    for (int r = 0; r < 16; r++){
      int b = g * 16 + r;
      smem[ml * 65 + b] = tm[(size_t)b * MK_ + m0 + ml];
    }
    __syncthreads();
    int bl = t & 63;
    #pragma unroll
    for (int r = 0; r < 16; r++){
      int m = g * 16 + r;
      tm_t[(size_t)(m0 + m) * 64 + bl] = smem[m * 65 + bl];
    }
  } else if (blk < 1566){
    int p0 = (blk - 1374) * 64;
    #pragma unroll
    for (int k = 0; k < 20; k++){
      int idx = k * 256 + t;
      int pl = idx / 80, j = idx - pl * 80;
      int p = p0 + pl;
      smem[j * 65 + pl] = (p < P_) ? skin[(size_t)p * J_ + j] : 0.f;
    }
    __syncthreads();
    #pragma unroll
    for (int k = 0; k < 20; k++){
      int idx = k * 256 + t;
      int j = idx >> 6, pl = idx & 63;
      w_t[(size_t)j * PW_ + p0 + pl] = smem[j * 65 + pl];
    }
  } else {
    if (t < 2) lacc[t] = 0.f;
  }
}

// ---- K2: detailkey partial GEMM. grid (6, 94). No LDS, no atomics.
//      4 waves share m-range [by*64, +64); wave wid owns b-slice [wid*16, +16).
//      Wd prefetched 4-deep (VMEM), tm_t rows 2-deep (SMEM s_load_dwordx16).
__global__ __launch_bounds__(256) void k_dkey(
    const float* __restrict__ tm_t, const float* __restrict__ Wd,
    float* __restrict__ part)
{
  int t = threadIdx.x;
  int lane = t & 63;
  int wid = __builtin_amdgcn_readfirstlane(t >> 6);
  int qt = blockIdx.x;
  int q = qt * 64 + lane;
  bool vq = q < Q_;
  int m0 = blockIdx.y * 64;
  const AS4 v16f* tr = univ16(tm_t);
  float acc[16];
  #pragma unroll
  for (int i = 0; i < 16; i++) acc[i] = 0.f;
  float wbuf[4];
  #pragma unroll
  for (int i = 0; i < 4; i++)
    wbuf[i] = vq ? Wd[(size_t)(m0 + i) * Q_ + q] : 0.f;
  v16f tb0 = tr[(size_t)(m0 + 0) * 4 + wid];
  v16f tb1 = tr[(size_t)(m0 + 1) * 4 + wid];
  #pragma unroll 4
  for (int mm = 0; mm < 60; mm++){
    float wd = wbuf[mm & 3];
    wbuf[mm & 3] = vq ? Wd[(size_t)(m0 + mm + 4) * Q_ + q] : 0.f;
    v16f tv = tb0; tb0 = tb1;
    tb1 = tr[(size_t)(m0 + mm + 2) * 4 + wid];
    #pragma unroll
    for (int i = 0; i < 16; i++) acc[i] = fmaf(tv[i], wd, acc[i]);
  }
  #pragma unroll
  for (int mm = 60; mm < 64; mm++){
    float wd = wbuf[mm & 3];
    v16f tv = tb0; tb0 = tb1;
    if (mm < 62) tb1 = tr[(size_t)(m0 + mm + 2) * 4 + wid];
    #pragma unroll
    for (int i = 0; i < 16; i++) acc[i] = fmaf(tv[i], wd, acc[i]);
  }
  float* pb = part + ((size_t)blockIdx.y * 6 + qt) * 4096 + (size_t)(wid * 16) * 64;
  #pragma unroll
  for (int i = 0; i < 16; i++) pb[i * 64 + lane] = acc[i];
}

// ---- K3: reduce partials + bd -> dk_t[q*64+b]. 680 blocks, 8-way d-split per j.
__global__ __launch_bounds__(256) void k_dkred(
    const float* __restrict__ part, const float* __restrict__ bd,
    float* __restrict__ dk_t, int S)
{
  int t = threadIdx.x;
  int jj = blockIdx.x * 32 + (t >> 3);   // 680*32 = 21760 = B_*Q_ exactly
  int dl = t & 7;
  int b = jj / Q_, q = jj - b * Q_;
  int qt = q >> 6, ql = q & 63;
  const float* pp = part + (size_t)qt * 4096 + b * 64 + ql;
  float s = 0.f;
  for (int d = dl; d < S; d += 8) s += pp[(size_t)d * 6 * 4096];
  s += __shfl_xor(s, 1); s += __shfl_xor(s, 2); s += __shfl_xor(s, 4);
  if (dl == 0) dk_t[q * 64 + b] = bd[q] + s;
}

// ---- K4: detail einsum, q-split across gridDim.y for occupancy; 2-stage
//      pipeline (groups of 5 q); writes RAW accumulation (scale moved to k_skin).
//      Last y-block -> out[1..], others -> stg0.
__global__ __launch_bounds__(512) void k_detail(
    const float* __restrict__ DPSD, const float* __restrict__ dk_t,
    float* __restrict__ stg0, float* __restrict__ out,
    float* __restrict__ lacc, int qn)
{
  int t = threadIdx.x;
  int lane = t & 63;
  int wid = __builtin_amdgcn_readfirstlane(t >> 6);  // 0..7
  int b0 = wid * 8;
  int e = blockIdx.x * 64 + lane;
  bool ve = e < NE_;
  int q0 = blockIdx.y * qn;
  const AS4 v8f* dkv = univ8(dk_t + b0);
  const float* Dp = DPSD + e;
  float acc[8];
  #pragma unroll
  for (int i = 0; i < 8; i++) acc[i] = 0.f;
  float sq = 0.f;
  float dc[5], dn[5];
  #pragma unroll
  for (int i = 0; i < 5; i++)
    dc[i] = ve ? Dp[(size_t)(q0 + i) * NE_] : 0.f;
  int ng = qn / 5;
  for (int g = 0; g < ng; g++){
    int qq = q0 + g * 5;
    if (g + 1 < ng){
      #pragma unroll
      for (int i = 0; i < 5; i++)
        dn[i] = ve ? Dp[(size_t)(qq + 5 + i) * NE_] : 0.f;
    }
    v8f r0 = dkv[(qq + 0) * 8];
    v8f r1 = dkv[(qq + 1) * 8];
    v8f r2 = dkv[(qq + 2) * 8];
    v8f r3 = dkv[(qq + 3) * 8];
    v8f r4 = dkv[(qq + 4) * 8];
    if (wid == 0){
      #pragma unroll
      for (int i = 0; i < 5; i++) sq = fmaf(dc[i], dc[i], sq);
    }
    #pragma unroll
    for (int i = 0; i < 8; i++){
      acc[i] = fmaf(r0[i], dc[0], acc[i]);
      acc[i] = fmaf(r1[i], dc[1], acc[i]);
      acc[i] = fmaf(r2[i], dc[2], acc[i]);
      acc[i] = fmaf(r3[i], dc[3], acc[i]);
      acc[i] = fmaf(r4[i], dc[4], acc[i]);
    }
    #pragma unroll
    for (int i = 0; i < 5; i++) dc[i] = dn[i];
  }
  if (ve){
    bool toOut = (blockIdx.y + 1 == gridDim.y);
    float* dst = toOut ? (out + 1 + e) : (stg0 + e);
    #pragma unroll
    for (int i = 0; i < 8; i++)
      dst[(size_t)(b0 + i) * NE_] = acc[i];
  }
  if (wid == 0){
    #pragma unroll
    for (int off = 32; off; off >>= 1) sq += __shfl_xor(sq, off);
    if (lane == 0) atomicAdd(&lacc[1], sq);
  }
}

// ---- K5: LBS skinning; G rows via s_load; combines detail halves + scale.
__global__ __launch_bounds__(256) void k_skin(
    const float* __restrict__ G, const float* __restrict__ w_t,
    const float* __restrict__ rest, const float* __restrict__ in_pc,
    const float* __restrict__ stg0, const float* __restrict__ rstd,
    const float* __restrict__ rmean,
    float* __restrict__ out, float* __restrict__ lacc, int two)
{
  int t = threadIdx.x;
  int lane = t & 63;
  int wid = __builtin_amdgcn_readfirstlane(t >> 6);  // 0..3
  int p  = blockIdx.x * 64 + lane;
  int bA = blockIdx.y * 8 + wid * 2;
  const AS4 v4f* gA = univ4(G + (size_t)bA * J_ * 12);
  const AS4 v4f* gB = univ4(G + ((size_t)bA + 1) * J_ * 12);
  float accA[12], accB[12];
  #pragma unroll
  for (int c = 0; c < 12; c++){ accA[c] = 0.f; accB[c] = 0.f; }
  const float* wp = w_t + p;
  #pragma unroll 4
  for (int j = 0; j < J_; j++){
    float w = wp[(size_t)j * PW_];
    v4f a0 = gA[j * 3 + 0], a1 = gA[j * 3 + 1], a2 = gA[j * 3 + 2];
    v4f c0 = gB[j * 3 + 0], c1 = gB[j * 3 + 1], c2 = gB[j * 3 + 2];
    #pragma unroll
    for (int c = 0; c < 4; c++){
      accA[c]     = fmaf(w, a0[c], accA[c]);
      accA[4 + c] = fmaf(w, a1[c], accA[4 + c]);
      accA[8 + c] = fmaf(w, a2[c], accA[8 + c]);
      accB[c]     = fmaf(w, c0[c], accB[c]);
      accB[4 + c] = fmaf(w, c1[c], accB[4 + c]);
      accB[8 + c] = fmaf(w, c2[c], accB[8 + c]);
    }
  }
  bool vp = p < P_;
  float vx = 0.f, vy = 0.f, vz = 0.f;
  if (vp){ vx = rest[p * 3]; vy = rest[p * 3 + 1]; vz = rest[p * 3 + 2]; }
  float srs[3], srm[3];
  #pragma unroll
  for (int x = 0; x < 3; x++){ srs[x] = rstd[x]; srm[x] = rmean[x]; }
  float lsum = 0.f;
  if (vp){
    size_t baseA = ((size_t)bA * P_ + p) * 3;
    size_t baseB = baseA + (size_t)P_ * 3;
    #pragma unroll
    for (int x = 0; x < 3; x++){
      float det = out[1 + baseA + x];
      if (two) det += stg0[baseA + x];
      float v = fmaf(accA[x*4+0], vx, fmaf(accA[x*4+1], vy, fmaf(accA[x*4+2], vz, accA[x*4+3])));
      v += fmaf(det, srs[x], srm[x]);
      lsum += fabsf(in_pc[baseA + x] - v);
      out[1 + baseA + x] = v;
    }
    #pragma unroll
    for (int x = 0; x < 3; x++){
      float det = out[1 + baseB + x];
      if (two) det += stg0[baseB + x];
      float v = fmaf(accB[x*4+0], vx, fmaf(accB[x*4+1], vy, fmaf(accB[x*4+2], vz, accB[x*4+3])));
      v += fmaf(det, srs[x], srm[x]);
      lsum += fabsf(in_pc[baseB + x] - v);
      out[1 + baseB + x] = v;
    }
  }
  #pragma unroll
  for (int off = 32; off; off >>= 1) lsum += __shfl_xor(lsum, off);
  __shared__ float red[4];
  if (lane == 0) red[wid] = lsum;
  __syncthreads();
  if (t == 0) atomicAdd(&lacc[0], red[0] + red[1] + red[2] + red[3]);
}

// ---- K6: finalize scalar loss
__global__ void k_finalize(const float* __restrict__ lacc, float* __restrict__ out){
  if (threadIdx.x == 0 && blockIdx.x == 0){
    float loss = lacc[0] * (1.f / 2356416.f) + 1e-4f * (lacc[1] * (1.f / 12518460.f));
    out[0] = loss;
  }
}

extern "C" void kernel_launch(void* const* d_in, const int* in_sizes, int n_in,
                              void* d_out, int out_size, void* d_ws, size_t ws_size,
                              hipStream_t stream){
  const float* in_pc = (const float*)d_in[0];
  const float* rest  = (const float*)d_in[2];
  const float* skin  = (const float*)d_in[3];
  const float* mwl   = (const float*)d_in[4];
  const float* query = (const float*)d_in[5];
  const float* cps   = (const float*)d_in[6];
  const float* cpm   = (const float*)d_in[7];
  const float* cts   = (const float*)d_in[8];
  const float* ctm   = (const float*)d_in[9];
  const float* W1    = (const float*)d_in[10];
  const float* b1    = (const float*)d_in[11];
  const float* W2    = (const float*)d_in[12];
  const float* b2    = (const float*)d_in[13];
  const float* tm    = (const float*)d_in[14];
  const float* Wd    = (const float*)d_in[15];
  const float* bd    = (const float*)d_in[16];
  const float* DPSD  = (const float*)d_in[17];
  const float* rstd  = (const float*)d_in[18];
  const float* rmean = (const float*)d_in[19];
  float* out = (float*)d_out;

  float* ws   = (float*)d_ws;
  float* G    = ws;                 // 61440
  float* dk_t = G + 61440;          // 21760
  float* lacc = dk_t + 21760;       // 64 (pad)
  float* tm_t = lacc + 64;          // 385024
  float* w_t  = tm_t + 385024;      // 983040
  float* un   = w_t + 983040;       // union: part (94*24576=2310144) then stg0 (2356416)
  // part is dead before k_detail writes stg0 -> alias them.

  size_t have = ws_size / 4;
  int nqh = (have >= (size_t)(1451328 + 2356416)) ? 2 : 1;
  int qn = Q_ / nqh;

  k_prep    <<<1567, 256, 0, stream>>>(query, mwl, tm, W1, b1, W2, b2,
                                       cps, cpm, cts, ctm, skin,
                                       G, tm_t, w_t, lacc);
  k_dkey    <<<dim3(6, 94), 256, 0, stream>>>(tm_t, Wd, un);
  k_dkred   <<<680, 256, 0, stream>>>(un, bd, dk_t, 94);
  k_detail  <<<dim3(576, nqh), 512, 0, stream>>>(DPSD, dk_t, un, out, lacc, qn);
  k_skin    <<<dim3(192, 8), 256, 0, stream>>>(G, w_t, rest, in_pc, un, rstd, rmean,
                                               out, lacc, nqh - 1);
  k_finalize<<<1, 64, 0, stream>>>(lacc, out);
}